// Round 1
// baseline (6665.902 us; speedup 1.0000x reference)
//
#include <hip/hip_runtime.h>

#define S 2048
#define NH 32
#define NEGF (-1e30f)

using bf16x8 = __attribute__((ext_vector_type(8))) __bf16;
using f32x4  = __attribute__((ext_vector_type(4))) float;
typedef unsigned int u32;
typedef unsigned short u16;
typedef unsigned long long u64;

__device__ __forceinline__ float blo(u32 u){ return __uint_as_float(u << 16); }
__device__ __forceinline__ float bhi(u32 u){ return __uint_as_float(u & 0xffff0000u); }
__device__ __forceinline__ u16 f2bf(float f){
  u32 u = __float_as_uint(f);
  u32 r = (u + 0x7fffu + ((u >> 16) & 1u)) >> 16;
  return (u16)r;
}
__device__ __forceinline__ u32 fkey(float f){
  u32 u = __float_as_uint(f);
  return (u & 0x80000000u) ? ~u : (u | 0x80000000u);
}

// ---------------- f32 -> bf16 conversion (4 elems/thread) ----------------
__global__ __launch_bounds__(256) void cvt_bf16(const float* __restrict__ src,
                                                u32* __restrict__ dst, int n4) {
  int gid = blockIdx.x*256 + threadIdx.x;
  if (gid >= n4) return;
  float4 v = ((const float4*)src)[gid];
  uint2 o;
  o.x = (u32)f2bf(v.x) | ((u32)f2bf(v.y) << 16);
  o.y = (u32)f2bf(v.z) | ((u32)f2bf(v.w) << 16);
  ((uint2*)dst)[gid] = o;
}

// ---------------- fp32 GEMM: C[M,N] = A[M,K] * W[N,K]^T ----------------
__global__ __launch_bounds__(256) void gemm_f32(const float* __restrict__ A,
                                                const float* __restrict__ W,
                                                float* __restrict__ C,
                                                int M, int N, int K) {
  __shared__ float As[16][65];
  __shared__ float Bs[16][65];
  const int t = threadIdx.x;
  const int m0 = blockIdx.y * 64, n0 = blockIdx.x * 64;
  const int ty = t >> 4, tx = t & 15;
  float acc[4][4] = {};
  for (int k0 = 0; k0 < K; k0 += 16) {
    __syncthreads();
    #pragma unroll
    for (int s2 = 0; s2 < 4; ++s2) {
      int idx = t + (s2 << 8);
      int r = idx >> 4, c = idx & 15;
      float a = 0.f, b = 0.f;
      if (m0 + r < M) a = A[(size_t)(m0+r)*K + k0 + c];
      if (n0 + r < N) b = W[(size_t)(n0+r)*K + k0 + c];
      As[c][r] = a; Bs[c][r] = b;
    }
    __syncthreads();
    #pragma unroll
    for (int c = 0; c < 16; ++c) {
      float av[4], bv[4];
      #pragma unroll
      for (int x = 0; x < 4; ++x) { av[x] = As[c][ty*4+x]; bv[x] = Bs[c][tx*4+x]; }
      #pragma unroll
      for (int x = 0; x < 4; ++x)
        #pragma unroll
        for (int y = 0; y < 4; ++y) acc[x][y] += av[x]*bv[y];
    }
  }
  #pragma unroll
  for (int x = 0; x < 4; ++x)
    #pragma unroll
    for (int y = 0; y < 4; ++y) {
      int row = m0 + ty*4 + x, col = n0 + tx*4 + y;
      if (row < M && col < N) C[(size_t)row*N + col] = acc[x][y];
    }
}

// ---------------- bf16 MFMA GEMM: C = A[M,K]*W[N,K]^T, 128x128 tile ----------------
template<int OUTBF>
__global__ __launch_bounds__(256) void gemm_bf16k(const u16* __restrict__ A,
                                                  const u16* __restrict__ W,
                                                  void* __restrict__ C,
                                                  int M, int N, int K) {
  __shared__ __bf16 As[128][40];
  __shared__ __bf16 Bs[128][40];
  const int t = threadIdx.x;
  const int m0 = blockIdx.y << 7, n0 = blockIdx.x << 7;
  const int wave = t >> 6, lane = t & 63;
  const int wm = (wave >> 1) << 6, wn = (wave & 1) << 6;
  const int lr = lane & 15, ls = lane >> 4;
  f32x4 acc[4][4] = {};
  for (int k0 = 0; k0 < K; k0 += 32) {
    __syncthreads();
    #pragma unroll
    for (int s2 = 0; s2 < 2; ++s2) {
      int idx = t + (s2 << 8);
      int r = idx >> 2, c4 = (idx & 3) << 3;
      uint4 av = {0,0,0,0}, bv = {0,0,0,0};
      int gm = m0 + r, gn = n0 + r;
      if (gm < M) av = *(const uint4*)(A + (size_t)gm*K + k0 + c4);
      if (gn < N) bv = *(const uint4*)(W + (size_t)gn*K + k0 + c4);
      *(uint4*)(&As[r][c4]) = av;
      *(uint4*)(&Bs[r][c4]) = bv;
    }
    __syncthreads();
    bf16x8 af[4], bfr[4];
    #pragma unroll
    for (int x = 0; x < 4; ++x) af[x]  = *(const bf16x8*)(&As[wm + x*16 + lr][ls*8]);
    #pragma unroll
    for (int x = 0; x < 4; ++x) bfr[x] = *(const bf16x8*)(&Bs[wn + x*16 + lr][ls*8]);
    #pragma unroll
    for (int mi = 0; mi < 4; ++mi)
      #pragma unroll
      for (int ni = 0; ni < 4; ++ni)
        acc[mi][ni] = __builtin_amdgcn_mfma_f32_16x16x32_bf16(af[mi], bfr[ni], acc[mi][ni], 0, 0, 0);
  }
  #pragma unroll
  for (int mi = 0; mi < 4; ++mi)
    #pragma unroll
    for (int ni = 0; ni < 4; ++ni)
      #pragma unroll
      for (int r = 0; r < 4; ++r) {
        int row = m0 + wm + mi*16 + ls*4 + r;
        int col = n0 + wn + ni*16 + lr;
        if (row < M && col < N) {
          float v = acc[mi][ni][r];
          if (OUTBF) ((u16*)C)[(size_t)row*N + col] = f2bf(v);
          else       ((float*)C)[(size_t)row*N + col] = v;
        }
      }
}

// ---------------- RMSNorm (q path, 1536 cols, writes f32 in-place + bf16) ----------------
__global__ __launch_bounds__(256) void rms_q_kernel(float* __restrict__ qa,
                                                    const float* __restrict__ w,
                                                    u16* __restrict__ qres_b) {
  const int row = blockIdx.x, t = threadIdx.x;
  float* x = qa + (size_t)row*1536;
  float xs[6];
  float ss = 0.f;
  #pragma unroll
  for (int k = 0; k < 6; ++k) { xs[k] = x[t + k*256]; ss += xs[k]*xs[k]; }
  __shared__ float red[256];
  red[t] = ss; __syncthreads();
  for (int o = 128; o > 0; o >>= 1) { if (t < o) red[t] += red[t+o]; __syncthreads(); }
  float rms = rsqrtf(red[0]/1536.f + 1e-6f);
  #pragma unroll
  for (int k = 0; k < 6; ++k) {
    int c = t + k*256;
    float v = w[c] * (xs[k] * rms);
    x[c] = v;
    qres_b[(size_t)row*1536 + c] = f2bf(v);
  }
}

// ---------------- RMSNorm (kv path, first 512 of 576 cols -> bf16) ----------------
__global__ __launch_bounds__(256) void rms_kv_kernel(const float* __restrict__ ckv,
                                                     const float* __restrict__ w,
                                                     u16* __restrict__ kcomp) {
  const int row = blockIdx.x, t = threadIdx.x;
  const float* x = ckv + (size_t)row*576;
  float xs[2];
  float ss = 0.f;
  #pragma unroll
  for (int k = 0; k < 2; ++k) { xs[k] = x[t + k*256]; ss += xs[k]*xs[k]; }
  __shared__ float red[256];
  red[t] = ss; __syncthreads();
  for (int o = 128; o > 0; o >>= 1) { if (t < o) red[t] += red[t+o]; __syncthreads(); }
  float rms = rsqrtf(red[0]/512.f + 1e-6f);
  #pragma unroll
  for (int k = 0; k < 2; ++k) {
    int c = t + k*256;
    kcomp[(size_t)row*512 + c] = f2bf(w[c] * (xs[k] * rms));
  }
}

// ---------------- RoPE on q (in-place, bf16, dims 192..255) ----------------
__global__ __launch_bounds__(256) void rope_q_kernel(u16* __restrict__ q,
                                                     const float* __restrict__ cosb,
                                                     const float* __restrict__ sinb) {
  int gid = blockIdx.x*256 + threadIdx.x;      // 2048*32*32
  if (gid >= 2048*32*32) return;
  int i = gid >> 10, rem = gid & 1023;
  int h = rem >> 5, dd = rem & 31;
  size_t base = (size_t)i*8192 + h*256 + 192;
  float x1 = blo((u32)q[base+dd]   << 16 >> 16 << 16);   // decode bf16
  x1 = __uint_as_float(((u32)q[base+dd]) << 16);
  float x2 = __uint_as_float(((u32)q[base+dd+32]) << 16);
  float c1 = cosb[i*64+dd],   s1 = sinb[i*64+dd];
  float c2 = cosb[i*64+dd+32], s2 = sinb[i*64+dd+32];
  q[base+dd]    = f2bf(x1*c1 - x2*s1);
  q[base+dd+32] = f2bf(x2*c2 + x1*s2);
}

// ---------------- RoPE on k_pe (from ckv f32 cols 512..575 -> bf16 [2048,64]) ----------------
__global__ __launch_bounds__(256) void rope_k_kernel(const float* __restrict__ ckv,
                                                     const float* __restrict__ cosb,
                                                     const float* __restrict__ sinb,
                                                     u16* __restrict__ kpe) {
  int gid = blockIdx.x*256 + threadIdx.x;      // 2048*32
  if (gid >= 2048*32) return;
  int i = gid >> 5, dd = gid & 31;
  const float* xr = ckv + (size_t)i*576 + 512;
  float x1 = xr[dd], x2 = xr[dd+32];
  float c1 = cosb[i*64+dd],   s1 = sinb[i*64+dd];
  float c2 = cosb[i*64+dd+32], s2 = sinb[i*64+dd+32];
  kpe[(size_t)i*64+dd]    = f2bf(x1*c1 - x2*s1);
  kpe[(size_t)i*64+dd+32] = f2bf(x2*c2 + x1*s2);
}

// ---------------- transpose ik [2048,64] -> ikT [64,2048] ----------------
__global__ __launch_bounds__(256) void transpose_ik(const float* __restrict__ ik,
                                                    float* __restrict__ ikT) {
  int gid = blockIdx.x*256 + threadIdx.x;      // 64*2048
  if (gid >= 64*2048) return;
  int d = gid >> 11, j = gid & 2047;
  ikT[gid] = ik[(size_t)j*64 + d];
}

// ---------------- indexer scores + exact top-512 (bitonic, jax tie-break) ----------------
__global__ __launch_bounds__(256) void topk_kernel(const float* __restrict__ iqv,
                                                   const float* __restrict__ ikT,
                                                   const float* __restrict__ gates,
                                                   u32* __restrict__ maskbuf) {
  const int i = blockIdx.x, t = threadIdx.x;
  __shared__ float iqs[256];
  __shared__ float g[4];
  __shared__ u64 keys[2048];
  __shared__ u32 mk[64];
  iqs[t] = iqv[(size_t)i*256 + t];
  if (t < 4) g[t] = gates[(size_t)i*4 + t];
  if (t < 64) mk[t] = 0;
  __syncthreads();
  float g0 = g[0], g1 = g[1], g2 = g[2], g3 = g[3];
  for (int j0 = 0; j0 < 2048; j0 += 256) {
    int j = j0 + t;
    float s;
    if (j > i) s = NEGF;
    else {
      float d0=0.f, d1=0.f, d2=0.f, d3=0.f;
      #pragma unroll 16
      for (int dd = 0; dd < 64; ++dd) {
        float v = ikT[dd*2048 + j];
        d0 += iqs[dd]*v; d1 += iqs[64+dd]*v; d2 += iqs[128+dd]*v; d3 += iqs[192+dd]*v;
      }
      s = g0*fmaxf(d0,0.f) + g1*fmaxf(d1,0.f) + g2*fmaxf(d2,0.f) + g3*fmaxf(d3,0.f);
    }
    keys[j] = ((u64)fkey(s) << 32) | (u32)(0xFFFFFFFFu - (u32)j);
  }
  __syncthreads();
  for (int k2 = 2; k2 <= 2048; k2 <<= 1) {
    for (int jj = k2 >> 1; jj > 0; jj >>= 1) {
      #pragma unroll 1
      for (int q8 = 0; q8 < 8; ++q8) {
        int x = t + (q8 << 8);
        int y = x ^ jj;
        if (y > x) {
          u64 kx = keys[x], ky = keys[y];
          if ((kx < ky) == ((x & k2) == 0)) { keys[x] = ky; keys[y] = kx; }
        }
      }
      __syncthreads();
    }
  }
  u32 ja = 0xFFFFFFFFu - (u32)(keys[t] & 0xFFFFFFFFull);
  u32 jb = 0xFFFFFFFFu - (u32)(keys[t+256] & 0xFFFFFFFFull);
  atomicOr(&mk[ja >> 5], 1u << (ja & 31));
  atomicOr(&mk[jb >> 5], 1u << (jb & 31));
  __syncthreads();
  if (t < 64) maskbuf[(size_t)i*64 + t] = mk[t];
}

// ---------------- attention pass1: raw scores -> probs buf, flash PV -> attn ----------------
__global__ __launch_bounds__(256) void attn_pass1(const u16* __restrict__ qb,
                                                  const u16* __restrict__ kvb,
                                                  const u16* __restrict__ kpeb,
                                                  const u32* __restrict__ maskbuf,
                                                  float* __restrict__ probs,
                                                  u16* __restrict__ attnb,
                                                  float* __restrict__ Mb,
                                                  float* __restrict__ Lb) {
  const int h = blockIdx.y;
  const int i0 = blockIdx.x << 4;
  const int t = threadIdx.x;
  const int i_loc = t >> 4, lan = t & 15;
  const int i_g = i0 + i_loc;
  __shared__ float Qs[16][257];
  __shared__ u32 KsW[32][129];
  __shared__ u32 VsW[32][129];
  __shared__ float Ss[16][33];
  __shared__ float mM[16], mL[16], mAl[16], mMn[16];
  const u32* qw  = (const u32*)qb;     // q row = 4096 words
  const u32* kvw = (const u32*)kvb;    // kv row = 7168 words
  const u32* kpw = (const u32*)kpeb;   // kpe row = 32 words
  for (int idx = t; idx < 16*128; idx += 256) {
    int r = idx >> 7, w = idx & 127;
    u32 u = qw[(size_t)(i0 + r)*4096 + h*128 + w];
    Qs[r][2*w] = blo(u); Qs[r][2*w+1] = bhi(u);
  }
  if (t < 16) { mM[t] = -INFINITY; mL[t] = 0.f; }
  float acc[16] = {};
  const int jt_end = (i0 + 15) >> 5;
  for (int jt = 0; jt <= jt_end; ++jt) {
    const int j0 = jt << 5;
    __syncthreads();
    for (int idx = t; idx < 32*128; idx += 256) {
      int r = idx >> 7, w = idx & 127;
      size_t jr = (size_t)(j0 + r);
      u32 ku = (w < 96) ? kvw[jr*7168 + h*224 + w] : kpw[jr*32 + (w - 96)];
      KsW[r][w] = ku;
      VsW[r][w] = kvw[jr*7168 + h*224 + 96 + w];
    }
    __syncthreads();
    const int j_a = j0 + 2*lan;
    const u32 mword = maskbuf[(size_t)i_g*64 + jt];
    const bool ok_a = (j_a <= i_g)     && ((mword >> (2*lan))   & 1u);
    const bool ok_b = (j_a + 1 <= i_g) && ((mword >> (2*lan+1)) & 1u);
    float s_a = NEGF, s_b = NEGF;
    if (ok_a || ok_b) {
      float d0 = 0.f, d1 = 0.f;
      const u32* ka = &KsW[2*lan][0];
      const u32* kb = &KsW[2*lan+1][0];
      #pragma unroll 8
      for (int w = 0; w < 128; ++w) {
        float q0 = Qs[i_loc][2*w], q1 = Qs[i_loc][2*w+1];
        u32 ua = ka[w], ub = kb[w];
        d0 += q0*blo(ua) + q1*bhi(ua);
        d1 += q0*blo(ub) + q1*bhi(ub);
      }
      if (ok_a) s_a = d0 * 0.0625f;
      if (ok_b) s_b = d1 * 0.0625f;
    }
    Ss[i_loc][2*lan] = s_a; Ss[i_loc][2*lan+1] = s_b;
    { float2 st; st.x = s_a; st.y = s_b;
      *(float2*)(probs + ((size_t)h*S + i_g)*S + j_a) = st; }
    __syncthreads();
    if (t < 16) {
      float rm = NEGF;
      #pragma unroll
      for (int j = 0; j < 32; ++j) rm = fmaxf(rm, Ss[t][j]);
      float mo = mM[t];
      float mn = fmaxf(mo, rm);
      mAl[t] = __expf(mo - mn);
      mMn[t] = mn; mM[t] = mn;
    }
    __syncthreads();
    float mn = mMn[i_loc];
    float p_a = __expf(s_a - mn), p_b = __expf(s_b - mn);
    Ss[i_loc][2*lan] = p_a; Ss[i_loc][2*lan+1] = p_b;
    __syncthreads();
    if (t < 16) {
      float sum = 0.f;
      #pragma unroll
      for (int j = 0; j < 32; ++j) sum += Ss[t][j];
      mL[t] = mL[t]*mAl[t] + sum;
    }
    float al = mAl[i_loc];
    #pragma unroll
    for (int r = 0; r < 16; ++r) acc[r] *= al;
    for (int j = 0; j < 32; ++j) {
      float p = Ss[i_loc][j];
      if (p != 0.f) {
        const u32* vr = &VsW[j][0];
        #pragma unroll
        for (int r = 0; r < 8; ++r) {
          u32 u = vr[lan + 16*r];
          acc[2*r]   += p * blo(u);
          acc[2*r+1] += p * bhi(u);
        }
      }
    }
  }
  __syncthreads();
  float invl = 1.f / mL[i_loc];
  u32* aw = (u32*)attnb;
  size_t abase = (size_t)i_g*4096 + h*128;
  #pragma unroll
  for (int r = 0; r < 8; ++r) {
    u32 pk = (u32)f2bf(acc[2*r]*invl) | ((u32)f2bf(acc[2*r+1]*invl) << 16);
    aw[abase + lan + 16*r] = pk;
  }
  if (t < 16) {
    Mb[(size_t)h*S + i0 + t] = mM[t];
    Lb[(size_t)h*S + i0 + t] = mL[t];
  }
}

// ---------------- attention pass2: in-place softmax normalize of probs ----------------
__global__ __launch_bounds__(256) void attn_pass2(float* __restrict__ probs,
                                                  const float* __restrict__ Mb,
                                                  const float* __restrict__ Lb) {
  const int i = blockIdx.x, h = blockIdx.y, t = threadIdx.x;
  const float m = Mb[(size_t)h*S + i];
  const float invl = 1.f / Lb[(size_t)h*S + i];
  float* row = probs + ((size_t)h*S + i)*S;
  #pragma unroll
  for (int k = 0; k < 2; ++k) {
    int c0 = 4*t + 1024*k;
    float4 v = *(float4*)(row + c0);
    float4 o;
    o.x = (c0+0 <= i) ? __expf(v.x - m)*invl : 0.f;
    o.y = (c0+1 <= i) ? __expf(v.y - m)*invl : 0.f;
    o.z = (c0+2 <= i) ? __expf(v.z - m)*invl : 0.f;
    o.w = (c0+3 <= i) ? __expf(v.w - m)*invl : 0.f;
    *(float4*)(row + c0) = o;
  }
}

// ---------------- host launch ----------------
extern "C" void kernel_launch(void* const* d_in, const int* in_sizes, int n_in,
                              void* d_out, int out_size, void* d_ws, size_t ws_size,
                              hipStream_t stream) {
  (void)in_sizes; (void)n_in; (void)out_size; (void)ws_size;
  const float* hidden    = (const float*)d_in[0];
  const float* cosb      = (const float*)d_in[1];
  const float* sinb      = (const float*)d_in[2];
  const float* q_a_w     = (const float*)d_in[3];
  const float* q_a_ln    = (const float*)d_in[4];
  const float* q_b_w     = (const float*)d_in[5];
  const float* kv_a_w    = (const float*)d_in[6];
  const float* kv_a_ln   = (const float*)d_in[7];
  const float* kv_b_w    = (const float*)d_in[8];
  const float* o_w       = (const float*)d_in[9];
  const float* idx_q_w   = (const float*)d_in[10];
  const float* idx_k_w   = (const float*)d_in[11];
  const float* idx_gate_w= (const float*)d_in[12];
  float* out   = (float*)d_out;
  float* probs = out + (size_t)2048*4096;

  char* wp = (char*)d_ws;
  auto alloc = [&](size_t bytes) { char* p = wp; wp += (bytes + 255) & ~(size_t)255; return p; };
  float* qa      = (float*)alloc((size_t)2048*1536*4);
  float* iq      = (float*)alloc((size_t)2048*256*4);
  float* ik      = (float*)alloc((size_t)2048*64*4);
  float* ikT     = (float*)alloc((size_t)64*2048*4);
  float* gates   = (float*)alloc((size_t)2048*4*4);
  float* ckv     = (float*)alloc((size_t)2048*576*4);
  u16* hidden_b  = (u16*)alloc((size_t)2048*4096*2);
  u16* qres_b    = (u16*)alloc((size_t)2048*1536*2);
  u16* qbw_b     = (u16*)alloc((size_t)8192*1536*2);
  u16* kvaw_b    = (u16*)alloc((size_t)576*4096*2);
  u16* kvbw_b    = (u16*)alloc((size_t)14336*512*2);
  u16* ow_b      = (u16*)alloc((size_t)4096*8192*2);
  u16* qB        = (u16*)alloc((size_t)2048*8192*2);
  u16* kcomp_b   = (u16*)alloc((size_t)2048*512*2);
  u16* kpe_b     = (u16*)alloc((size_t)2048*64*2);
  u16* kvB       = (u16*)alloc((size_t)2048*14336*2);
  u16* attn_b    = (u16*)alloc((size_t)2048*8192*2);
  u32* maskb     = (u32*)alloc((size_t)2048*64*4);
  float* Mb      = (float*)alloc((size_t)32*2048*4);
  float* Lb      = (float*)alloc((size_t)32*2048*4);

  dim3 blk(256);
  // bf16 copies
  cvt_bf16<<<8192,  blk, 0, stream>>>(hidden, (u32*)hidden_b, 2097152);
  cvt_bf16<<<12288, blk, 0, stream>>>(q_b_w,  (u32*)qbw_b,   3145728);
  cvt_bf16<<<2304,  blk, 0, stream>>>(kv_a_w, (u32*)kvaw_b,   589824);
  cvt_bf16<<<7168,  blk, 0, stream>>>(kv_b_w, (u32*)kvbw_b,  1835008);
  cvt_bf16<<<32768, blk, 0, stream>>>(o_w,    (u32*)ow_b,    8388608);
  // fp32 precision path (indexer)
  gemm_f32<<<dim3(24,32), blk, 0, stream>>>(hidden, q_a_w,      qa,    2048, 1536, 4096);
  gemm_f32<<<dim3(1,32),  blk, 0, stream>>>(hidden, idx_k_w,    ik,    2048, 64,   4096);
  gemm_f32<<<dim3(1,32),  blk, 0, stream>>>(hidden, idx_gate_w, gates, 2048, 4,    4096);
  rms_q_kernel<<<2048, blk, 0, stream>>>(qa, q_a_ln, qres_b);
  gemm_f32<<<dim3(4,32),  blk, 0, stream>>>(qa, idx_q_w, iq, 2048, 256, 1536);
  transpose_ik<<<512, blk, 0, stream>>>(ik, ikT);
  // bf16 path
  gemm_bf16k<0><<<dim3(5,16),   blk, 0, stream>>>(hidden_b, kvaw_b, ckv, 2048, 576,   4096);
  rms_kv_kernel<<<2048, blk, 0, stream>>>(ckv, kv_a_ln, kcomp_b);
  rope_k_kernel<<<256, blk, 0, stream>>>(ckv, cosb, sinb, kpe_b);
  gemm_bf16k<1><<<dim3(64,16),  blk, 0, stream>>>(qres_b, qbw_b, qB, 2048, 8192, 1536);
  rope_q_kernel<<<8192, blk, 0, stream>>>(qB, cosb, sinb);
  gemm_bf16k<1><<<dim3(112,16), blk, 0, stream>>>(kcomp_b, kvbw_b, kvB, 2048, 14336, 512);
  // top-k + attention
  topk_kernel<<<2048, blk, 0, stream>>>(iq, ikT, gates, maskb);
  attn_pass1<<<dim3(128,32), blk, 0, stream>>>(qB, kvB, kpe_b, maskb, probs, attn_b, Mb, Lb);
  attn_pass2<<<dim3(2048,32), blk, 0, stream>>>(probs, Mb, Lb);
  // output projection
  gemm_bf16k<0><<<dim3(32,16), blk, 0, stream>>>(attn_b, ow_b, out, 2048, 4096, 8192);
}

// Round 2
// 4030.951 us; speedup vs baseline: 1.6537x; 1.6537x over previous
//
#include <hip/hip_runtime.h>

#define S 2048
#define NH 32
#define NEGF (-1e30f)

using bf16x8 = __attribute__((ext_vector_type(8))) __bf16;
using f32x4  = __attribute__((ext_vector_type(4))) float;
typedef unsigned int u32;
typedef unsigned short u16;
typedef unsigned long long u64;

__device__ __forceinline__ float blo(u32 u){ return __uint_as_float(u << 16); }
__device__ __forceinline__ float bhi(u32 u){ return __uint_as_float(u & 0xffff0000u); }
__device__ __forceinline__ u16 f2bf(float f){
  u32 u = __float_as_uint(f);
  u32 r = (u + 0x7fffu + ((u >> 16) & 1u)) >> 16;
  return (u16)r;
}
__device__ __forceinline__ u32 fkey(float f){
  u32 u = __float_as_uint(f);
  return (u & 0x80000000u) ? ~u : (u | 0x80000000u);
}

// ---------------- f32 -> bf16 conversion (4 elems/thread) ----------------
__global__ __launch_bounds__(256) void cvt_bf16(const float* __restrict__ src,
                                                u32* __restrict__ dst, int n4) {
  int gid = blockIdx.x*256 + threadIdx.x;
  if (gid >= n4) return;
  float4 v = ((const float4*)src)[gid];
  uint2 o;
  o.x = (u32)f2bf(v.x) | ((u32)f2bf(v.y) << 16);
  o.y = (u32)f2bf(v.z) | ((u32)f2bf(v.w) << 16);
  ((uint2*)dst)[gid] = o;
}

// ---------------- concat idx_k_w (64x4096) + idx_gate_w (4x4096) -> [68,4096] ----------------
__global__ __launch_bounds__(256) void concat_ikg(const float* __restrict__ ikw,
                                                  const float* __restrict__ gw,
                                                  float* __restrict__ dst) {
  int gid = blockIdx.x*256 + threadIdx.x;   // 68*1024 float4
  if (gid >= 69632) return;
  float4 v = (gid < 65536) ? ((const float4*)ikw)[gid] : ((const float4*)gw)[gid - 65536];
  ((float4*)dst)[gid] = v;
}

// ---------------- fp32 GEMM: C[M,N] = A[M,K] * W[N,K]^T ----------------
__global__ __launch_bounds__(256) void gemm_f32(const float* __restrict__ A,
                                                const float* __restrict__ W,
                                                float* __restrict__ C,
                                                int M, int N, int K) {
  __shared__ float As[16][65];
  __shared__ float Bs[16][65];
  const int t = threadIdx.x;
  const int m0 = blockIdx.y * 64, n0 = blockIdx.x * 64;
  const int ty = t >> 4, tx = t & 15;
  float acc[4][4] = {};
  for (int k0 = 0; k0 < K; k0 += 16) {
    __syncthreads();
    #pragma unroll
    for (int s2 = 0; s2 < 4; ++s2) {
      int idx = t + (s2 << 8);
      int r = idx >> 4, c = idx & 15;
      float a = 0.f, b = 0.f;
      if (m0 + r < M) a = A[(size_t)(m0+r)*K + k0 + c];
      if (n0 + r < N) b = W[(size_t)(n0+r)*K + k0 + c];
      As[c][r] = a; Bs[c][r] = b;
    }
    __syncthreads();
    #pragma unroll
    for (int c = 0; c < 16; ++c) {
      float av[4], bv[4];
      #pragma unroll
      for (int x = 0; x < 4; ++x) { av[x] = As[c][ty*4+x]; bv[x] = Bs[c][tx*4+x]; }
      #pragma unroll
      for (int x = 0; x < 4; ++x)
        #pragma unroll
        for (int y = 0; y < 4; ++y) acc[x][y] += av[x]*bv[y];
    }
  }
  #pragma unroll
  for (int x = 0; x < 4; ++x)
    #pragma unroll
    for (int y = 0; y < 4; ++y) {
      int row = m0 + ty*4 + x, col = n0 + tx*4 + y;
      if (row < M && col < N) C[(size_t)row*N + col] = acc[x][y];
    }
}

// ---------------- bf16 MFMA GEMM: C = A[M,K]*W[N,K]^T, 128x128 tile ----------------
template<int OUTBF>
__global__ __launch_bounds__(256) void gemm_bf16k(const u16* __restrict__ A,
                                                  const u16* __restrict__ W,
                                                  void* __restrict__ C,
                                                  int M, int N, int K) {
  __shared__ __bf16 As[128][40];
  __shared__ __bf16 Bs[128][40];
  const int t = threadIdx.x;
  const int m0 = blockIdx.y << 7, n0 = blockIdx.x << 7;
  const int wave = t >> 6, lane = t & 63;
  const int wm = (wave >> 1) << 6, wn = (wave & 1) << 6;
  const int lr = lane & 15, ls = lane >> 4;
  f32x4 acc[4][4] = {};
  for (int k0 = 0; k0 < K; k0 += 32) {
    __syncthreads();
    #pragma unroll
    for (int s2 = 0; s2 < 2; ++s2) {
      int idx = t + (s2 << 8);
      int r = idx >> 2, c4 = (idx & 3) << 3;
      uint4 av = {0,0,0,0}, bv = {0,0,0,0};
      int gm = m0 + r, gn = n0 + r;
      if (gm < M) av = *(const uint4*)(A + (size_t)gm*K + k0 + c4);
      if (gn < N) bv = *(const uint4*)(W + (size_t)gn*K + k0 + c4);
      *(uint4*)(&As[r][c4]) = av;
      *(uint4*)(&Bs[r][c4]) = bv;
    }
    __syncthreads();
    bf16x8 af[4], bfr[4];
    #pragma unroll
    for (int x = 0; x < 4; ++x) af[x]  = *(const bf16x8*)(&As[wm + x*16 + lr][ls*8]);
    #pragma unroll
    for (int x = 0; x < 4; ++x) bfr[x] = *(const bf16x8*)(&Bs[wn + x*16 + lr][ls*8]);
    #pragma unroll
    for (int mi = 0; mi < 4; ++mi)
      #pragma unroll
      for (int ni = 0; ni < 4; ++ni)
        acc[mi][ni] = __builtin_amdgcn_mfma_f32_16x16x32_bf16(af[mi], bfr[ni], acc[mi][ni], 0, 0, 0);
  }
  #pragma unroll
  for (int mi = 0; mi < 4; ++mi)
    #pragma unroll
    for (int ni = 0; ni < 4; ++ni)
      #pragma unroll
      for (int r = 0; r < 4; ++r) {
        int row = m0 + wm + mi*16 + ls*4 + r;
        int col = n0 + wn + ni*16 + lr;
        if (row < M && col < N) {
          float v = acc[mi][ni][r];
          if (OUTBF) ((u16*)C)[(size_t)row*N + col] = f2bf(v);
          else       ((float*)C)[(size_t)row*N + col] = v;
        }
      }
}

// ---------------- RMSNorm (q path, 1536 cols, writes f32 in-place + bf16) ----------------
__global__ __launch_bounds__(256) void rms_q_kernel(float* __restrict__ qa,
                                                    const float* __restrict__ w,
                                                    u16* __restrict__ qres_b) {
  const int row = blockIdx.x, t = threadIdx.x;
  float* x = qa + (size_t)row*1536;
  float xs[6];
  float ss = 0.f;
  #pragma unroll
  for (int k = 0; k < 6; ++k) { xs[k] = x[t + k*256]; ss += xs[k]*xs[k]; }
  __shared__ float red[256];
  red[t] = ss; __syncthreads();
  for (int o = 128; o > 0; o >>= 1) { if (t < o) red[t] += red[t+o]; __syncthreads(); }
  float rms = rsqrtf(red[0]/1536.f + 1e-6f);
  #pragma unroll
  for (int k = 0; k < 6; ++k) {
    int c = t + k*256;
    float v = w[c] * (xs[k] * rms);
    x[c] = v;
    qres_b[(size_t)row*1536 + c] = f2bf(v);
  }
}

// ---------------- RMSNorm (kv path, first 512 of 576 cols -> bf16) ----------------
__global__ __launch_bounds__(256) void rms_kv_kernel(const float* __restrict__ ckv,
                                                     const float* __restrict__ w,
                                                     u16* __restrict__ kcomp) {
  const int row = blockIdx.x, t = threadIdx.x;
  const float* x = ckv + (size_t)row*576;
  float xs[2];
  float ss = 0.f;
  #pragma unroll
  for (int k = 0; k < 2; ++k) { xs[k] = x[t + k*256]; ss += xs[k]*xs[k]; }
  __shared__ float red[256];
  red[t] = ss; __syncthreads();
  for (int o = 128; o > 0; o >>= 1) { if (t < o) red[t] += red[t+o]; __syncthreads(); }
  float rms = rsqrtf(red[0]/512.f + 1e-6f);
  #pragma unroll
  for (int k = 0; k < 2; ++k) {
    int c = t + k*256;
    kcomp[(size_t)row*512 + c] = f2bf(w[c] * (xs[k] * rms));
  }
}

// ---------------- RoPE on q (in-place, bf16, dims 192..255) ----------------
__global__ __launch_bounds__(256) void rope_q_kernel(u16* __restrict__ q,
                                                     const float* __restrict__ cosb,
                                                     const float* __restrict__ sinb) {
  int gid = blockIdx.x*256 + threadIdx.x;      // 2048*32*32
  if (gid >= 2048*32*32) return;
  int i = gid >> 10, rem = gid & 1023;
  int h = rem >> 5, dd = rem & 31;
  size_t base = (size_t)i*8192 + h*256 + 192;
  float x1 = __uint_as_float(((u32)q[base+dd]) << 16);
  float x2 = __uint_as_float(((u32)q[base+dd+32]) << 16);
  float c1 = cosb[i*64+dd],   s1 = sinb[i*64+dd];
  float c2 = cosb[i*64+dd+32], s2 = sinb[i*64+dd+32];
  q[base+dd]    = f2bf(x1*c1 - x2*s1);
  q[base+dd+32] = f2bf(x2*c2 + x1*s2);
}

// ---------------- RoPE on k_pe (from ckv f32 cols 512..575 -> bf16 [2048,64]) ----------------
__global__ __launch_bounds__(256) void rope_k_kernel(const float* __restrict__ ckv,
                                                     const float* __restrict__ cosb,
                                                     const float* __restrict__ sinb,
                                                     u16* __restrict__ kpe) {
  int gid = blockIdx.x*256 + threadIdx.x;      // 2048*32
  if (gid >= 2048*32) return;
  int i = gid >> 5, dd = gid & 31;
  const float* xr = ckv + (size_t)i*576 + 512;
  float x1 = xr[dd], x2 = xr[dd+32];
  float c1 = cosb[i*64+dd],   s1 = sinb[i*64+dd];
  float c2 = cosb[i*64+dd+32], s2 = sinb[i*64+dd+32];
  kpe[(size_t)i*64+dd]    = f2bf(x1*c1 - x2*s1);
  kpe[(size_t)i*64+dd+32] = f2bf(x2*c2 + x1*s2);
}

// ---------------- transpose ikg [2048,68] -> ikT [64,2048] ----------------
__global__ __launch_bounds__(256) void transpose_ik(const float* __restrict__ ikg,
                                                    float* __restrict__ ikT) {
  int gid = blockIdx.x*256 + threadIdx.x;      // 64*2048
  if (gid >= 64*2048) return;
  int d = gid >> 11, j = gid & 2047;
  ikT[gid] = ikg[(size_t)j*68 + d];
}

// ---------------- indexer scores + exact top-512 (bitonic, jax tie-break) ----------------
__global__ __launch_bounds__(256) void topk_kernel(const float* __restrict__ iqv,
                                                   const float* __restrict__ ikT,
                                                   const float* __restrict__ ikg,
                                                   u32* __restrict__ maskbuf) {
  const int i = blockIdx.x, t = threadIdx.x;
  __shared__ float iqs[256];
  __shared__ float g[4];
  __shared__ u64 keys[2048];
  __shared__ u32 mk[64];
  iqs[t] = iqv[(size_t)i*256 + t];
  if (t < 4) g[t] = ikg[(size_t)i*68 + 64 + t];
  if (t < 64) mk[t] = 0;
  __syncthreads();
  float g0 = g[0], g1 = g[1], g2 = g[2], g3 = g[3];
  for (int j0 = 0; j0 < 2048; j0 += 256) {
    int j = j0 + t;
    float s;
    if (j > i) s = NEGF;
    else {
      float d0=0.f, d1=0.f, d2=0.f, d3=0.f;
      #pragma unroll 16
      for (int dd = 0; dd < 64; ++dd) {
        float v = ikT[dd*2048 + j];
        d0 += iqs[dd]*v; d1 += iqs[64+dd]*v; d2 += iqs[128+dd]*v; d3 += iqs[192+dd]*v;
      }
      s = g0*fmaxf(d0,0.f) + g1*fmaxf(d1,0.f) + g2*fmaxf(d2,0.f) + g3*fmaxf(d3,0.f);
    }
    keys[j] = ((u64)fkey(s) << 32) | (u32)(0xFFFFFFFFu - (u32)j);
  }
  __syncthreads();
  for (int k2 = 2; k2 <= 2048; k2 <<= 1) {
    for (int jj = k2 >> 1; jj > 0; jj >>= 1) {
      #pragma unroll 1
      for (int q8 = 0; q8 < 8; ++q8) {
        int x = t + (q8 << 8);
        int y = x ^ jj;
        if (y > x) {
          u64 kx = keys[x], ky = keys[y];
          if ((kx < ky) == ((x & k2) == 0)) { keys[x] = ky; keys[y] = kx; }
        }
      }
      __syncthreads();
    }
  }
  u32 ja = 0xFFFFFFFFu - (u32)(keys[t] & 0xFFFFFFFFull);
  u32 jb = 0xFFFFFFFFu - (u32)(keys[t+256] & 0xFFFFFFFFull);
  atomicOr(&mk[ja >> 5], 1u << (ja & 31));
  atomicOr(&mk[jb >> 5], 1u << (jb & 31));
  __syncthreads();
  if (t < 64) maskbuf[(size_t)i*64 + t] = mk[t];
}

// ---------------- MFMA flash attention pass1 ----------------
// block: 1 head x 64 queries (4 waves x 16q). Q in A-frags, K in LDS,
// V transposed in LDS (u32 key-pair packed), P via LDS round-trip.
__global__ __launch_bounds__(256, 3) void attn_pass1(
    const u16* __restrict__ qb, const u16* __restrict__ kvb,
    const u16* __restrict__ kpeb, const u32* __restrict__ maskbuf,
    float* __restrict__ probs, u16* __restrict__ attnb,
    float* __restrict__ Mb, float* __restrict__ Lb) {
  const int h = blockIdx.y;
  const int i0 = blockIdx.x << 6;
  const int t = threadIdx.x;
  const int w = t >> 6;
  const int lane = t & 63;
  const int l15 = lane & 15, l4 = lane >> 4;
  const int i0w = i0 + (w << 4);

  __shared__ u16 Ks[32][264];       // keys x 256 dims, +8 pad (row 528B, 16-aligned)
  __shared__ u32 Vt[256][20];       // vdim x 16 key-pairs (row 80B, 16-aligned)
  __shared__ u16 Ps[4][16][40];     // per-wave P transform buffer

  // Q fragments: A[m=l15][k=l4*8+e], 8 k-steps of 32
  bf16x8 qf[8];
  {
    const u16* qrow = qb + (size_t)(i0w + l15)*8192 + h*256 + l4*8;
    #pragma unroll
    for (int ks = 0; ks < 8; ++ks)
      qf[ks] = *(const bf16x8*)(qrow + ks*32);
  }
  f32x4 Of[16] = {};
  float mr[4] = {-INFINITY,-INFINITY,-INFINITY,-INFINITY};
  float lr[4] = {0.f,0.f,0.f,0.f};

  const int jt_end = (i0 + 63) >> 5;
  for (int jt = 0; jt <= jt_end; ++jt) {
    const int j0 = jt << 5;
    __syncthreads();
    // stage K rows (nope 192 + rope 64)
    #pragma unroll
    for (int it = 0; it < 4; ++it) {
      int idx = t + (it << 8);
      int r = idx >> 5, c8 = idx & 31;
      const u16* src = (c8 < 24)
        ? kvb + (size_t)(j0 + r)*14336 + h*448 + c8*8
        : kpeb + (size_t)(j0 + r)*64 + (c8 - 24)*8;
      *(uint4*)(&Ks[r][c8*8]) = *(const uint4*)src;
    }
    // stage V transposed: key-pair u32 packing, staggered element order
    #pragma unroll
    for (int it = 0; it < 2; ++it) {
      int idx = t + (it << 8);
      int rp = idx >> 5, c8 = idx & 31;
      const u16* v0p = kvb + (size_t)(j0 + 2*rp)*14336 + h*448 + 192 + c8*8;
      uint4 a = *(const uint4*)v0p;
      uint4 b = *(const uint4*)(v0p + 14336);
      u16 va[8], vb[8];
      *(uint4*)va = a; *(uint4*)vb = b;
      #pragma unroll
      for (int s2 = 0; s2 < 8; ++s2) {
        int e = (s2 + c8) & 7;
        Vt[c8*8 + e][rp] = (u32)va[e] | ((u32)vb[e] << 16);
      }
    }
    __syncthreads();
    if (j0 > i0w + 15) continue;   // causal wave-level skip

    // mask words for this wave's 16 rows
    u32 mw = maskbuf[(size_t)(i0w + l15)*64 + jt];
    u32 mword[4];
    #pragma unroll
    for (int r = 0; r < 4; ++r) mword[r] = __shfl(mw, (l4<<2) + r, 64);

    // S = Q K^T (2 key sub-tiles of 16)
    f32x4 sacc[2] = {};
    #pragma unroll
    for (int nt = 0; nt < 2; ++nt)
      #pragma unroll
      for (int ks = 0; ks < 8; ++ks) {
        bf16x8 kf = *(const bf16x8*)(&Ks[nt*16 + l15][ks*32 + l4*8]);
        sacc[nt] = __builtin_amdgcn_mfma_f32_16x16x32_bf16(qf[ks], kf, sacc[nt], 0, 0, 0);
      }

    // mask + scale; write raw scores (16-wide segments with any topk bit)
    float sv[2][4];
    #pragma unroll
    for (int nt = 0; nt < 2; ++nt)
      #pragma unroll
      for (int r = 0; r < 4; ++r) {
        int i_r = i0w + (l4<<2) + r;
        int j = j0 + nt*16 + l15;
        bool ok = (j <= i_r) && ((mword[r] >> (nt*16 + l15)) & 1u);
        sv[nt][r] = ok ? sacc[nt][r]*0.0625f : NEGF;
      }
    #pragma unroll
    for (int r = 0; r < 4; ++r) {
      int i_r = i0w + (l4<<2) + r;
      #pragma unroll
      for (int nt = 0; nt < 2; ++nt)
        if ((mword[r] >> (nt*16)) & 0xFFFFu)
          probs[((size_t)h*S + i_r)*S + j0 + nt*16 + l15] = sv[nt][r];
    }

    // online softmax (rows spread over 16-lane groups; shfl_xor reduce)
    float alpha[4];
    #pragma unroll
    for (int r = 0; r < 4; ++r) {
      float v = fmaxf(sv[0][r], sv[1][r]);
      v = fmaxf(v, __shfl_xor(v, 1, 64));
      v = fmaxf(v, __shfl_xor(v, 2, 64));
      v = fmaxf(v, __shfl_xor(v, 4, 64));
      v = fmaxf(v, __shfl_xor(v, 8, 64));
      float mn = fmaxf(mr[r], v);
      alpha[r] = (mn == mr[r]) ? 1.f : __expf(mr[r] - mn);
      mr[r] = mn;
    }
    float p0v[4], p1v[4];
    #pragma unroll
    for (int r = 0; r < 4; ++r) {
      float p0 = __expf(sv[0][r] - mr[r]);   // NEGF -> underflow 0; all-masked row self-corrects via alpha=0 later
      float p1 = __expf(sv[1][r] - mr[r]);
      p0v[r] = p0; p1v[r] = p1;
      float rs = p0 + p1;
      rs += __shfl_xor(rs, 1, 64);
      rs += __shfl_xor(rs, 2, 64);
      rs += __shfl_xor(rs, 4, 64);
      rs += __shfl_xor(rs, 8, 64);
      lr[r] = lr[r]*alpha[r] + rs;
    }

    // P -> LDS (C-layout write), read back as A-frag
    #pragma unroll
    for (int r = 0; r < 4; ++r) {
      Ps[w][(l4<<2)+r][l15]      = f2bf(p0v[r]);
      Ps[w][(l4<<2)+r][16 + l15] = f2bf(p1v[r]);
    }
    bf16x8 pf = *(const bf16x8*)(&Ps[w][l15][l4*8]);

    // rescale O, then PV
    #pragma unroll
    for (int vt = 0; vt < 16; ++vt)
      #pragma unroll
      for (int r = 0; r < 4; ++r)
        Of[vt][r] *= alpha[r];
    #pragma unroll
    for (int vt = 0; vt < 16; ++vt) {
      bf16x8 vf = *(const bf16x8*)(&Vt[vt*16 + l15][l4*4]);
      Of[vt] = __builtin_amdgcn_mfma_f32_16x16x32_bf16(pf, vf, Of[vt], 0, 0, 0);
    }
  }

  // epilogue
  float invl[4];
  #pragma unroll
  for (int r = 0; r < 4; ++r) invl[r] = 1.f / lr[r];
  #pragma unroll
  for (int vt = 0; vt < 16; ++vt)
    #pragma unroll
    for (int r = 0; r < 4; ++r) {
      int i_r = i0w + (l4<<2) + r;
      attnb[(size_t)i_r*8192 + h*256 + vt*16 + l15] = f2bf(Of[vt][r]*invl[r]);
    }
  if (l15 == 0) {
    #pragma unroll
    for (int r = 0; r < 4; ++r) {
      Mb[(size_t)h*S + i0w + (l4<<2) + r] = mr[r];
      Lb[(size_t)h*S + i0w + (l4<<2) + r] = lr[r];
    }
  }
}

// ---------------- pass2: mask-aware softmax normalize of probs ----------------
__global__ __launch_bounds__(256) void attn_pass2(float* __restrict__ probs,
                                                  const float* __restrict__ Mb,
                                                  const float* __restrict__ Lb,
                                                  const u32* __restrict__ maskbuf) {
  const int i = blockIdx.x, h = blockIdx.y, t = threadIdx.x;
  const int j0 = t << 3;
  float* row = probs + ((size_t)h*S + i)*S;
  u32 bits = (maskbuf[(size_t)i*64 + (j0 >> 5)] >> (j0 & 31)) & 0xFFu;
  float4 o0 = {0.f,0.f,0.f,0.f}, o1 = {0.f,0.f,0.f,0.f};
  if (bits != 0 && j0 <= i) {
    const float m = Mb[(size_t)h*S + i];
    const float invl = 1.f / Lb[(size_t)h*S + i];
    float4 v0 = *(const float4*)(row + j0);
    float4 v1 = *(const float4*)(row + j0 + 4);
    o0.x = (((bits>>0)&1u) && j0+0 <= i) ? __expf(v0.x - m)*invl : 0.f;
    o0.y = (((bits>>1)&1u) && j0+1 <= i) ? __expf(v0.y - m)*invl : 0.f;
    o0.z = (((bits>>2)&1u) && j0+2 <= i) ? __expf(v0.z - m)*invl : 0.f;
    o0.w = (((bits>>3)&1u) && j0+3 <= i) ? __expf(v0.w - m)*invl : 0.f;
    o1.x = (((bits>>4)&1u) && j0+4 <= i) ? __expf(v1.x - m)*invl : 0.f;
    o1.y = (((bits>>5)&1u) && j0+5 <= i) ? __expf(v1.y - m)*invl : 0.f;
    o1.z = (((bits>>6)&1u) && j0+6 <= i) ? __expf(v1.z - m)*invl : 0.f;
    o1.w = (((bits>>7)&1u) && j0+7 <= i) ? __expf(v1.w - m)*invl : 0.f;
  }
  *(float4*)(row + j0) = o0;
  *(float4*)(row + j0 + 4) = o1;
}

// ---------------- host launch ----------------
extern "C" void kernel_launch(void* const* d_in, const int* in_sizes, int n_in,
                              void* d_out, int out_size, void* d_ws, size_t ws_size,
                              hipStream_t stream) {
  (void)in_sizes; (void)n_in; (void)out_size; (void)ws_size;
  const float* hidden    = (const float*)d_in[0];
  const float* cosb      = (const float*)d_in[1];
  const float* sinb      = (const float*)d_in[2];
  const float* q_a_w     = (const float*)d_in[3];
  const float* q_a_ln    = (const float*)d_in[4];
  const float* q_b_w     = (const float*)d_in[5];
  const float* kv_a_w    = (const float*)d_in[6];
  const float* kv_a_ln   = (const float*)d_in[7];
  const float* kv_b_w    = (const float*)d_in[8];
  const float* o_w       = (const float*)d_in[9];
  const float* idx_q_w   = (const float*)d_in[10];
  const float* idx_k_w   = (const float*)d_in[11];
  const float* idx_gate_w= (const float*)d_in[12];
  float* out   = (float*)d_out;
  float* probs = out + (size_t)2048*4096;

  char* wp = (char*)d_ws;
  auto alloc = [&](size_t bytes) { char* p = wp; wp += (bytes + 255) & ~(size_t)255; return p; };
  float* qa      = (float*)alloc((size_t)2048*1536*4);
  float* iq      = (float*)alloc((size_t)2048*256*4);
  float* ikg     = (float*)alloc((size_t)68*4096*4);
  float* ikgo    = (float*)alloc((size_t)2048*68*4);
  float* ikT     = (float*)alloc((size_t)64*2048*4);
  float* ckv     = (float*)alloc((size_t)2048*576*4);
  u16* hidden_b  = (u16*)alloc((size_t)2048*4096*2);
  u16* qres_b    = (u16*)alloc((size_t)2048*1536*2);
  u16* qbw_b     = (u16*)alloc((size_t)8192*1536*2);
  u16* kvaw_b    = (u16*)alloc((size_t)576*4096*2);
  u16* kvbw_b    = (u16*)alloc((size_t)14336*512*2);
  u16* ow_b      = (u16*)alloc((size_t)4096*8192*2);
  u16* qB        = (u16*)alloc((size_t)2048*8192*2);
  u16* kcomp_b   = (u16*)alloc((size_t)2048*512*2);
  u16* kpe_b     = (u16*)alloc((size_t)2048*64*2);
  u16* kvB       = (u16*)alloc((size_t)2048*14336*2);
  u16* attn_b    = (u16*)alloc((size_t)2048*8192*2);
  u32* maskb     = (u32*)alloc((size_t)2048*64*4);
  float* Mb      = (float*)alloc((size_t)32*2048*4);
  float* Lb      = (float*)alloc((size_t)32*2048*4);

  dim3 blk(256);
  // bf16 copies
  cvt_bf16<<<8192,  blk, 0, stream>>>(hidden, (u32*)hidden_b, 2097152);
  cvt_bf16<<<12288, blk, 0, stream>>>(q_b_w,  (u32*)qbw_b,   3145728);
  cvt_bf16<<<2304,  blk, 0, stream>>>(kv_a_w, (u32*)kvaw_b,   589824);
  cvt_bf16<<<7168,  blk, 0, stream>>>(kv_b_w, (u32*)kvbw_b,  1835008);
  cvt_bf16<<<32768, blk, 0, stream>>>(o_w,    (u32*)ow_b,    8388608);
  concat_ikg<<<272, blk, 0, stream>>>(idx_k_w, idx_gate_w, ikg);
  // fp32 precision path (indexer)
  gemm_f32<<<dim3(24,32), blk, 0, stream>>>(hidden, q_a_w, qa,   2048, 1536, 4096);
  gemm_f32<<<dim3(2,32),  blk, 0, stream>>>(hidden, ikg,   ikgo, 2048, 68,   4096);
  rms_q_kernel<<<2048, blk, 0, stream>>>(qa, q_a_ln, qres_b);
  gemm_f32<<<dim3(4,32),  blk, 0, stream>>>(qa, idx_q_w, iq, 2048, 256, 1536);
  transpose_ik<<<512, blk, 0, stream>>>(ikgo, ikT);
  // bf16 path
  gemm_bf16k<0><<<dim3(5,16),   blk, 0, stream>>>(hidden_b, kvaw_b, ckv, 2048, 576,   4096);
  rms_kv_kernel<<<2048, blk, 0, stream>>>(ckv, kv_a_ln, kcomp_b);
  rope_k_kernel<<<256, blk, 0, stream>>>(ckv, cosb, sinb, kpe_b);
  gemm_bf16k<1><<<dim3(64,16),  blk, 0, stream>>>(qres_b, qbw_b, qB, 2048, 8192, 1536);
  rope_q_kernel<<<8192, blk, 0, stream>>>(qB, cosb, sinb);
  gemm_bf16k<1><<<dim3(112,16), blk, 0, stream>>>(kcomp_b, kvbw_b, kvB, 2048, 14336, 512);
  // top-k + attention
  topk_kernel<<<2048, blk, 0, stream>>>(iq, ikT, ikgo, maskb);
  attn_pass1<<<dim3(32,32), blk, 0, stream>>>(qB, kvB, kpe_b, maskb, probs, attn_b, Mb, Lb);
  attn_pass2<<<dim3(2048,32), blk, 0, stream>>>(probs, Mb, Lb, maskb);
  // output projection
  gemm_bf16k<0><<<dim3(32,16), blk, 0, stream>>>(attn_b, ow_b, out, 2048, 4096, 8192);
}